// Round 5
// baseline (308.981 us; speedup 1.0000x reference)
//
#include <hip/hip_runtime.h>
#include <hip/hip_bf16.h>
#include <math.h>

// TopicRouter, two kernels:
//  A) router_logits: logits[B,8] = h @ gate_w^T + b. HBM-read-bound (96 MB).
//     R3/R4 plateaued at ~2.5 TB/s with 8 waves/CU (register-gate forced
//     __launch_bounds__(256,2)); per-wave in-flight bytes 6 vs 12 KB made no
//     difference -> limiter is wave-level parallelism, not per-wave ILP.
//     This version: gate in 24 KB LDS, BLOCK=512, launch_bounds(512,6)
//     -> ~24 waves/CU (3x). Per wave-iteration: 6 float4 burst loads,
//     2x8 dot products from LDS, butterfly reduce, one 64 B store.
//  B) router_topk: per-thread top-2 + softmax over logits (1 MB), coalesced.

constexpr int D  = 768;
constexpr int E  = 8;
constexpr int D4 = D / 4;          // 192 float4 per row
constexpr int BLOCK  = 512;        // 8 waves
constexpr int GRID_A = 1024;       // 8192 waves; 16384 pairs -> 2 per wave
constexpr int BLOCK_B = 256;

__device__ __forceinline__ float dot4acc(float4 a, float4 b, float acc) {
    acc = fmaf(a.x, b.x, acc);
    acc = fmaf(a.y, b.y, acc);
    acc = fmaf(a.z, b.z, acc);
    acc = fmaf(a.w, b.w, acc);
    return acc;
}
__device__ __forceinline__ float dot4(float4 a, float4 b) {
    return fmaf(a.x, b.x, fmaf(a.y, b.y, fmaf(a.z, b.z, a.w * b.w)));
}

// Reduce a[8] (per-expert partials) across 64 lanes.
// Returns: this lane's total for expert e = bitrev3(lane&7).
__device__ __forceinline__ float wave_reduce8(float a[8], int lane) {
    {   // xor 1: 8 -> 4 values
        const bool hi = lane & 1;
#pragma unroll
        for (int j = 0; j < 4; ++j) {
            float send = hi ? a[j] : a[j + 4];
            float recv = __shfl_xor(send, 1, 64);
            float keep = hi ? a[j + 4] : a[j];
            a[j] = keep + recv;
        }
    }
    {   // xor 2: 4 -> 2
        const bool hi = lane & 2;
#pragma unroll
        for (int j = 0; j < 2; ++j) {
            float send = hi ? a[j] : a[j + 2];
            float recv = __shfl_xor(send, 2, 64);
            float keep = hi ? a[j + 2] : a[j];
            a[j] = keep + recv;
        }
    }
    {   // xor 4: 2 -> 1
        const bool hi = lane & 4;
        float send = hi ? a[0] : a[1];
        float recv = __shfl_xor(send, 4, 64);
        float keep = hi ? a[1] : a[0];
        a[0] = keep + recv;
    }
    float v = a[0];
    v += __shfl_xor(v, 8, 64);
    v += __shfl_xor(v, 16, 64);
    v += __shfl_xor(v, 32, 64);
    return v;
}

__global__ __launch_bounds__(BLOCK, 6)
void router_logits_kernel(const float* __restrict__ h,
                          const float* __restrict__ gate_w,
                          const float* __restrict__ gate_b,
                          float* __restrict__ out_logits,
                          int B) {
    __shared__ float4 gs4[E * D4];   // 24 KB

    const int tid = threadIdx.x;
    const float4* gw4 = (const float4*)gate_w;
#pragma unroll
    for (int i = tid; i < E * D4; i += BLOCK) gs4[i] = gw4[i];
    __syncthreads();

    const int lane   = tid & 63;
    const int gwave  = blockIdx.x * (BLOCK / 64) + (tid >> 6);
    const int nwaves = gridDim.x * (BLOCK / 64);

    const int l3 = lane & 7;
    const int e_lane = ((l3 & 1) << 2) | (l3 & 2) | ((l3 >> 2) & 1);  // bitrev3
    const float bias = gate_b[e_lane];

    const float4* h4 = (const float4*)h;
    const int npairs = B >> 1;

    for (int p = gwave; p < npairs; p += nwaves) {
        const float4* hp = h4 + (size_t)p * (2 * D4) + lane;

        // Burst all 6 loads; compute below overlaps via fine-grained vmcnt,
        // and 24 waves/CU keep the request pipe fed across the stalls.
        float4 cv[6];
#pragma unroll
        for (int c = 0; c < 3; ++c) cv[c]     = hp[c * 64];        // row 2p
#pragma unroll
        for (int c = 0; c < 3; ++c) cv[3 + c] = hp[D4 + c * 64];   // row 2p+1

        float acc0[E], acc1[E];
#pragma unroll
        for (int e = 0; e < E; ++e) {
            float4 g0 = gs4[e * D4 + 0 * 64 + lane];
            float4 g1 = gs4[e * D4 + 1 * 64 + lane];
            float4 g2 = gs4[e * D4 + 2 * 64 + lane];
            float a0 = dot4(cv[0], g0);
            a0 = dot4acc(cv[1], g1, a0);
            a0 = dot4acc(cv[2], g2, a0);
            acc0[e] = a0;
            float a1 = dot4(cv[3], g0);
            a1 = dot4acc(cv[4], g1, a1);
            a1 = dot4acc(cv[5], g2, a1);
            acc1[e] = a1;
        }

        float va = wave_reduce8(acc0, lane) + bias;
        float vb = wave_reduce8(acc1, lane) + bias;

        // Lanes 0..15 write both rows' logits as one contiguous 64 B chunk.
        float v = (lane & 8) ? vb : va;
        if (lane < 16) out_logits[(size_t)p * 16 + (lane & 8) + e_lane] = v;
    }
}

__global__ __launch_bounds__(BLOCK_B)
void router_topk_kernel(const float* __restrict__ logits,
                        float* __restrict__ out_idx,
                        float* __restrict__ out_w,
                        int B) {
    const int t = blockIdx.x * BLOCK_B + threadIdx.x;
    if (t >= B) return;

    const float4* lp = (const float4*)(logits + (size_t)t * 8);
    float4 a = lp[0], b = lp[1];
    float l[8] = {a.x, a.y, a.z, a.w, b.x, b.y, b.z, b.w};

    // Stable top-2 (strict >): ties keep the lower expert index (lax.top_k).
    float v0 = l[0]; int i0 = 0;
    float v1 = -INFINITY; int i1 = -1;
#pragma unroll
    for (int e = 1; e < 8; ++e) {
        float x = l[e];
        bool gt0 = x > v0;
        bool gt1 = x > v1;
        float nv1 = gt0 ? v0 : (gt1 ? x : v1);
        int   ni1 = gt0 ? i0 : (gt1 ? e : i1);
        v1 = nv1; i1 = ni1;
        v0 = gt0 ? x : v0;
        i0 = gt0 ? e : i0;
    }
    float tt = expf(v1 - v0);
    float w0 = 1.0f / (1.0f + tt);
    float w1 = tt * w0;

    ((float2*)out_idx)[t] = make_float2((float)i0, (float)i1);
    ((float2*)out_w)[t]   = make_float2(w0, w1);
}

extern "C" void kernel_launch(void* const* d_in, const int* in_sizes, int n_in,
                              void* d_out, int out_size, void* d_ws, size_t ws_size,
                              hipStream_t stream) {
    const float* h      = (const float*)d_in[0];
    const float* gate_w = (const float*)d_in[1];
    const float* gate_b = (const float*)d_in[2];

    const int B = in_sizes[0] / D;   // 32768

    float* out        = (float*)d_out;
    float* out_idx    = out;                       // [B,2] indices as float
    float* out_w      = out + (size_t)B * 2;       // [B,2] weights
    float* out_logits = out + (size_t)B * 4;       // [B,8] logits

    router_logits_kernel<<<dim3(GRID_A), dim3(BLOCK), 0, stream>>>(
        h, gate_w, gate_b, out_logits, B);

    router_topk_kernel<<<dim3((B + BLOCK_B - 1) / BLOCK_B), dim3(BLOCK_B), 0, stream>>>(
        out_logits, out_idx, out_w, B);
}

// Round 6
// 151.152 us; speedup vs baseline: 2.0442x; 2.0442x over previous
//
#include <hip/hip_runtime.h>
#include <hip/hip_bf16.h>
#include <math.h>

// TopicRouter, two kernels:
//  A) router_logits: logits[B,8] = h @ gate_w^T + b. HBM-read-bound (96 MB).
//     Register shape copied from R1 (LDS gate, launch_bounds(256,4), VGPR=64,
//     proven no-spill), tail stripped (R3), coalesced 64 B logit store (R3).
//     GRID 2048 -> 6 resident blocks/CU (LDS-limited) ~= 24 waves/CU, 3x R3.
//     NO register prefetch buffer: R5 proved tight VGPR bounds make the
//     allocator spill it; TLP across 24 waves supplies the in-flight bytes.
//  B) router_topk: per-thread top-2 + softmax over logits (1 MB), coalesced.

constexpr int D  = 768;
constexpr int E  = 8;
constexpr int D4 = D / 4;          // 192 float4 per row
constexpr int BLOCK  = 256;        // 4 waves
constexpr int GRID_A = 2048;       // 8192 waves; 16384 pairs -> 2 per wave
constexpr int BLOCK_B = 256;

__device__ __forceinline__ float dot4acc(float4 a, float4 b, float acc) {
    acc = fmaf(a.x, b.x, acc);
    acc = fmaf(a.y, b.y, acc);
    acc = fmaf(a.z, b.z, acc);
    acc = fmaf(a.w, b.w, acc);
    return acc;
}
__device__ __forceinline__ float dot4(float4 a, float4 b) {
    return fmaf(a.x, b.x, fmaf(a.y, b.y, fmaf(a.z, b.z, a.w * b.w)));
}

// Reduce a[8] (per-expert partials) across 64 lanes.
// Returns: this lane's total for expert e = bitrev3(lane&7).
__device__ __forceinline__ float wave_reduce8(float a[8], int lane) {
    {   // xor 1: 8 -> 4 values
        const bool hi = lane & 1;
#pragma unroll
        for (int j = 0; j < 4; ++j) {
            float send = hi ? a[j] : a[j + 4];
            float recv = __shfl_xor(send, 1, 64);
            float keep = hi ? a[j + 4] : a[j];
            a[j] = keep + recv;
        }
    }
    {   // xor 2: 4 -> 2
        const bool hi = lane & 2;
#pragma unroll
        for (int j = 0; j < 2; ++j) {
            float send = hi ? a[j] : a[j + 2];
            float recv = __shfl_xor(send, 2, 64);
            float keep = hi ? a[j + 2] : a[j];
            a[j] = keep + recv;
        }
    }
    {   // xor 4: 2 -> 1
        const bool hi = lane & 4;
        float send = hi ? a[0] : a[1];
        float recv = __shfl_xor(send, 4, 64);
        float keep = hi ? a[1] : a[0];
        a[0] = keep + recv;
    }
    float v = a[0];
    v += __shfl_xor(v, 8, 64);
    v += __shfl_xor(v, 16, 64);
    v += __shfl_xor(v, 32, 64);
    return v;
}

__global__ __launch_bounds__(BLOCK, 4)
void router_logits_kernel(const float* __restrict__ h,
                          const float* __restrict__ gate_w,
                          const float* __restrict__ gate_b,
                          float* __restrict__ out_logits,
                          int B) {
    __shared__ float4 gs4[E * D4];   // 24 KB

    const int tid = threadIdx.x;
    const float4* gw4 = (const float4*)gate_w;
#pragma unroll
    for (int i = tid; i < E * D4; i += BLOCK) gs4[i] = gw4[i];
    __syncthreads();

    const int lane   = tid & 63;
    const int gwave  = blockIdx.x * (BLOCK / 64) + (tid >> 6);
    const int nwaves = gridDim.x * (BLOCK / 64);

    const int l3 = lane & 7;
    const int e_lane = ((l3 & 1) << 2) | (l3 & 2) | ((l3 >> 2) & 1);  // bitrev3
    const float bias = gate_b[e_lane];

    const float4* h4 = (const float4*)h;
    const int npairs = B >> 1;

    for (int p = gwave; p < npairs; p += nwaves) {
        const float4* hp = h4 + (size_t)p * (2 * D4) + lane;

        // Burst all 6 loads; fine-grained vmcnt overlaps them with the LDS
        // reads below, and ~24 waves/CU keep the memory pipe continuously fed.
        float4 cv[6];
#pragma unroll
        for (int c = 0; c < 3; ++c) cv[c]     = hp[c * 64];        // row 2p
#pragma unroll
        for (int c = 0; c < 3; ++c) cv[3 + c] = hp[D4 + c * 64];   // row 2p+1

        float acc0[E], acc1[E];
#pragma unroll
        for (int e = 0; e < E; ++e) {
            float4 g0 = gs4[e * D4 + 0 * 64 + lane];
            float4 g1 = gs4[e * D4 + 1 * 64 + lane];
            float4 g2 = gs4[e * D4 + 2 * 64 + lane];
            float a0 = dot4(cv[0], g0);
            a0 = dot4acc(cv[1], g1, a0);
            a0 = dot4acc(cv[2], g2, a0);
            acc0[e] = a0;
            float a1 = dot4(cv[3], g0);
            a1 = dot4acc(cv[4], g1, a1);
            a1 = dot4acc(cv[5], g2, a1);
            acc1[e] = a1;
        }

        float va = wave_reduce8(acc0, lane) + bias;
        float vb = wave_reduce8(acc1, lane) + bias;

        // Lanes 0..15 write both rows' logits as one contiguous 64 B chunk.
        float v = (lane & 8) ? vb : va;
        if (lane < 16) out_logits[(size_t)p * 16 + (lane & 8) + e_lane] = v;
    }
}

__global__ __launch_bounds__(BLOCK_B)
void router_topk_kernel(const float* __restrict__ logits,
                        float* __restrict__ out_idx,
                        float* __restrict__ out_w,
                        int B) {
    const int t = blockIdx.x * BLOCK_B + threadIdx.x;
    if (t >= B) return;

    const float4* lp = (const float4*)(logits + (size_t)t * 8);
    float4 a = lp[0], b = lp[1];
    float l[8] = {a.x, a.y, a.z, a.w, b.x, b.y, b.z, b.w};

    // Stable top-2 (strict >): ties keep the lower expert index (lax.top_k).
    float v0 = l[0]; int i0 = 0;
    float v1 = -INFINITY; int i1 = -1;
#pragma unroll
    for (int e = 1; e < 8; ++e) {
        float x = l[e];
        bool gt0 = x > v0;
        bool gt1 = x > v1;
        float nv1 = gt0 ? v0 : (gt1 ? x : v1);
        int   ni1 = gt0 ? i0 : (gt1 ? e : i1);
        v1 = nv1; i1 = ni1;
        v0 = gt0 ? x : v0;
        i0 = gt0 ? e : i0;
    }
    float tt = expf(v1 - v0);
    float w0 = 1.0f / (1.0f + tt);
    float w1 = tt * w0;

    ((float2*)out_idx)[t] = make_float2((float)i0, (float)i1);
    ((float2*)out_w)[t]   = make_float2(w0, w1);
}

extern "C" void kernel_launch(void* const* d_in, const int* in_sizes, int n_in,
                              void* d_out, int out_size, void* d_ws, size_t ws_size,
                              hipStream_t stream) {
    const float* h      = (const float*)d_in[0];
    const float* gate_w = (const float*)d_in[1];
    const float* gate_b = (const float*)d_in[2];

    const int B = in_sizes[0] / D;   // 32768

    float* out        = (float*)d_out;
    float* out_idx    = out;                       // [B,2] indices as float
    float* out_w      = out + (size_t)B * 2;       // [B,2] weights
    float* out_logits = out + (size_t)B * 4;       // [B,8] logits

    router_logits_kernel<<<dim3(GRID_A), dim3(BLOCK), 0, stream>>>(
        h, gate_w, gate_b, out_logits, B);

    router_topk_kernel<<<dim3((B + BLOCK_B - 1) / BLOCK_B), dim3(BLOCK_B), 0, stream>>>(
        out_logits, out_idx, out_w, B);
}

// Round 7
// 148.440 us; speedup vs baseline: 2.0815x; 1.0183x over previous
//
#include <hip/hip_runtime.h>
#include <hip/hip_bf16.h>
#include <math.h>

// TopicRouter, two kernels:
//  A) router_logits: logits[B,8] = h @ gate_w^T + b. HBM-read-bound (96 MB).
//     R4 (ILP) and R6 (TLP) both left a ~2.5 TB/s plateau -> the limiter is
//     the per-wave load-free window (burst / drain / ~1500-cyc compute
//     convoy). This version makes overlap structural: per-wave PRIVATE
//     double-buffered global_load_lds DMA. Loop: ds_read buf k (auto
//     vmcnt(0) waits only DMA k, issued last iter) -> issue fire-and-forget
//     DMA k+1 -> compute. DMA k+1 has the whole compute phase to land.
//     Gate in 96 VGPRs, no barriers (buffers wave-private), no reg prefetch.
//  B) router_topk: per-thread top-2 + softmax over logits (1 MB), coalesced.

constexpr int D  = 768;
constexpr int E  = 8;
constexpr int D4 = D / 4;          // 192 float4 per row
constexpr int BLOCK  = 256;        // 4 waves
constexpr int GRID_A = 768;        // 3072 waves = 3 blocks/CU resident
constexpr int BLOCK_B = 256;

typedef __attribute__((address_space(1))) const float4 gas_float4;
typedef __attribute__((address_space(3))) float4 las_float4;

__device__ __forceinline__ float dot4acc(float4 a, float4 b, float acc) {
    acc = fmaf(a.x, b.x, acc);
    acc = fmaf(a.y, b.y, acc);
    acc = fmaf(a.z, b.z, acc);
    acc = fmaf(a.w, b.w, acc);
    return acc;
}
__device__ __forceinline__ float dot4(float4 a, float4 b) {
    return fmaf(a.x, b.x, fmaf(a.y, b.y, fmaf(a.z, b.z, a.w * b.w)));
}

// Reduce a[8] (per-expert partials) across 64 lanes.
// Returns: this lane's total for expert e = bitrev3(lane&7).
__device__ __forceinline__ float wave_reduce8(float a[8], int lane) {
    {   // xor 1: 8 -> 4 values
        const bool hi = lane & 1;
#pragma unroll
        for (int j = 0; j < 4; ++j) {
            float send = hi ? a[j] : a[j + 4];
            float recv = __shfl_xor(send, 1, 64);
            float keep = hi ? a[j + 4] : a[j];
            a[j] = keep + recv;
        }
    }
    {   // xor 2: 4 -> 2
        const bool hi = lane & 2;
#pragma unroll
        for (int j = 0; j < 2; ++j) {
            float send = hi ? a[j] : a[j + 2];
            float recv = __shfl_xor(send, 2, 64);
            float keep = hi ? a[j + 2] : a[j];
            a[j] = keep + recv;
        }
    }
    {   // xor 4: 2 -> 1
        const bool hi = lane & 4;
        float send = hi ? a[0] : a[1];
        float recv = __shfl_xor(send, 4, 64);
        float keep = hi ? a[1] : a[0];
        a[0] = keep + recv;
    }
    float v = a[0];
    v += __shfl_xor(v, 8, 64);
    v += __shfl_xor(v, 16, 64);
    v += __shfl_xor(v, 32, 64);
    return v;
}

// Issue 6 fire-and-forget 16B-per-lane DMA loads: pair p of h -> this wave's
// LDS buffer. Global address is per-lane; LDS base is wave-uniform, HW
// deposits at base + lane*16.
__device__ __forceinline__ void dma_pair(const float4* __restrict__ h4, int p,
                                         int lane, float4* lds_base) {
    const float4* hp = h4 + (size_t)p * (2 * D4) + lane;
#pragma unroll
    for (int c = 0; c < 3; ++c)
        __builtin_amdgcn_global_load_lds((gas_float4*)(hp + c * 64),
                                         (las_float4*)(lds_base + c * 64),
                                         16, 0, 0);
#pragma unroll
    for (int c = 0; c < 3; ++c)
        __builtin_amdgcn_global_load_lds((gas_float4*)(hp + D4 + c * 64),
                                         (las_float4*)(lds_base + 192 + c * 64),
                                         16, 0, 0);
}

__global__ __launch_bounds__(BLOCK, 2)
void router_logits_kernel(const float* __restrict__ h,
                          const float* __restrict__ gate_w,
                          const float* __restrict__ gate_b,
                          float* __restrict__ out_logits,
                          int B) {
    // Per-wave private double buffers: 2 bufs x 4 waves x 6 KB = 48 KB.
    __shared__ float4 hbuf[2][BLOCK / 64][2 * D4];

    const int tid    = threadIdx.x;
    const int lane   = tid & 63;
    const int wave   = tid >> 6;
    const int gwave  = blockIdx.x * (BLOCK / 64) + wave;
    const int nwaves = gridDim.x * (BLOCK / 64);

    const int l3 = lane & 7;
    const int e_lane = ((l3 & 1) << 2) | (l3 & 2) | ((l3 >> 2) & 1);  // bitrev3
    const float bias = gate_b[e_lane];

    // Loop-invariant gate slice: 24 float4 = 96 VGPRs.
    const float4* gw4 = (const float4*)gate_w;
    float4 greg[24];
#pragma unroll
    for (int e = 0; e < E; ++e)
#pragma unroll
        for (int c = 0; c < 3; ++c)
            greg[e * 3 + c] = gw4[e * D4 + c * 64 + lane];

    const float4* h4 = (const float4*)h;
    const int npairs = B >> 1;

    int p = gwave;
    if (p >= npairs) return;

    int buf = 0;
    dma_pair(h4, p, lane, &hbuf[0][wave][0]);   // prime buffer 0

    while (true) {
        const int pn = p + nwaves;
        const bool more = (pn < npairs);   // wave-uniform

        // Read current buffer. The compiler's vmcnt wait inserted before
        // these ds_reads covers only the already-issued DMA for pair p —
        // the next pair's DMA is issued *after* this point.
        float4 cv[6];
        float4* cur = &hbuf[buf][wave][0];
#pragma unroll
        for (int c = 0; c < 3; ++c) cv[c]     = cur[c * 64 + lane];
#pragma unroll
        for (int c = 0; c < 3; ++c) cv[3 + c] = cur[192 + c * 64 + lane];

        // Fire-and-forget DMA for the next pair into the other buffer;
        // it has the entire compute/reduce/store phase to complete.
        if (more) dma_pair(h4, pn, lane, &hbuf[buf ^ 1][wave][0]);

        float acc0[E], acc1[E];
#pragma unroll
        for (int e = 0; e < E; ++e) {
            float a0 = dot4(cv[0], greg[e * 3 + 0]);
            a0 = dot4acc(cv[1], greg[e * 3 + 1], a0);
            a0 = dot4acc(cv[2], greg[e * 3 + 2], a0);
            acc0[e] = a0;
            float a1 = dot4(cv[3], greg[e * 3 + 0]);
            a1 = dot4acc(cv[4], greg[e * 3 + 1], a1);
            a1 = dot4acc(cv[5], greg[e * 3 + 2], a1);
            acc1[e] = a1;
        }

        float va = wave_reduce8(acc0, lane) + bias;
        float vb = wave_reduce8(acc1, lane) + bias;

        // Lanes 0..15 write both rows' logits as one contiguous 64 B chunk.
        float v = (lane & 8) ? vb : va;
        if (lane < 16) out_logits[(size_t)p * 16 + (lane & 8) + e_lane] = v;

        if (!more) break;
        p = pn;
        buf ^= 1;
    }
}

__global__ __launch_bounds__(BLOCK_B)
void router_topk_kernel(const float* __restrict__ logits,
                        float* __restrict__ out_idx,
                        float* __restrict__ out_w,
                        int B) {
    const int t = blockIdx.x * BLOCK_B + threadIdx.x;
    if (t >= B) return;

    const float4* lp = (const float4*)(logits + (size_t)t * 8);
    float4 a = lp[0], b = lp[1];
    float l[8] = {a.x, a.y, a.z, a.w, b.x, b.y, b.z, b.w};

    // Stable top-2 (strict >): ties keep the lower expert index (lax.top_k).
    float v0 = l[0]; int i0 = 0;
    float v1 = -INFINITY; int i1 = -1;
#pragma unroll
    for (int e = 1; e < 8; ++e) {
        float x = l[e];
        bool gt0 = x > v0;
        bool gt1 = x > v1;
        float nv1 = gt0 ? v0 : (gt1 ? x : v1);
        int   ni1 = gt0 ? i0 : (gt1 ? e : i1);
        v1 = nv1; i1 = ni1;
        v0 = gt0 ? x : v0;
        i0 = gt0 ? e : i0;
    }
    float tt = expf(v1 - v0);
    float w0 = 1.0f / (1.0f + tt);
    float w1 = tt * w0;

    ((float2*)out_idx)[t] = make_float2((float)i0, (float)i1);
    ((float2*)out_w)[t]   = make_float2(w0, w1);
}

extern "C" void kernel_launch(void* const* d_in, const int* in_sizes, int n_in,
                              void* d_out, int out_size, void* d_ws, size_t ws_size,
                              hipStream_t stream) {
    const float* h      = (const float*)d_in[0];
    const float* gate_w = (const float*)d_in[1];
    const float* gate_b = (const float*)d_in[2];

    const int B = in_sizes[0] / D;   // 32768

    float* out        = (float*)d_out;
    float* out_idx    = out;                       // [B,2] indices as float
    float* out_w      = out + (size_t)B * 2;       // [B,2] weights
    float* out_logits = out + (size_t)B * 4;       // [B,8] logits

    router_logits_kernel<<<dim3(GRID_A), dim3(BLOCK), 0, stream>>>(
        h, gate_w, gate_b, out_logits, B);

    router_topk_kernel<<<dim3((B + BLOCK_B - 1) / BLOCK_B), dim3(BLOCK_B), 0, stream>>>(
        out_logits, out_idx, out_w, B);
}